// Round 7
// baseline (823.143 us; speedup 1.0000x reference)
//
#include <hip/hip_runtime.h>
#include <hip/hip_bf16.h>

// LSTM  B=256, S=512, I=512, H=128, OUT=2
// R7: SWAPPED-OPERAND MFMA in the consumer (T12 pattern): since A/B fragment
//     address functions are symmetric, mfma(bfr, af, acc) computes
//     (h@Wh)^T with the SAME registers/LDS reads, landing gates lane-local:
//     lane (quad,lm), lm<4 holds batch lm, gate-cols w*16+quad*4+r, all 4
//     gates in acc[g][r]. The LDS transpose round-trip (ds_write_b128 +
//     lgkmcnt(0) + ds_read_b128, ~300cyc + gbw conflicts) is DELETED.
//     EW: 4 cells/lane on 16 active lanes (ILP-4 chains); h-write: one
//     ds_write_b64/lane; xg: 4 consecutive u64/lane (same bytes, coalesced).
//     NOTE: R5 showed ds_bpermute is half-wave-limited on gfx950 -- this
//     approach uses NO cross-lane primitives at all.
// R6 retained: hb stride 152 (af = single ds_read_b128), af-first ordering.
// R3 retained: coherence-neutral handshake (RELAXED wave-0 spin; xg via
//     RELAXED/AGENT 8B atomics = write-through / L2-bypass).
// R0 retained: sched_barrier(0) pins gl_lds/prefetch issue order, fences raw
//     s_barrier and same-wave-LDS waits.

typedef __attribute__((ext_vector_type(8))) short short8;      // 8 bf16
typedef __attribute__((ext_vector_type(4))) float floatx4;
typedef __attribute__((ext_vector_type(4))) unsigned short ushortx4;
typedef __attribute__((ext_vector_type(2))) unsigned int uint2v;

#define LOG2E 1.44269504088896340736f
#define NPROD 192
#define HBS 152              // hb row stride (shorts); 304B = 16B-multiple
#define HBUF (16 * HBS)      // one hb buffer (shorts)

__device__ __forceinline__ unsigned short f2bf(float f) {
  unsigned int u = __builtin_bit_cast(unsigned int, f);
  u = (u + 0x7fffu + ((u >> 16) & 1u)) >> 16;   // RNE
  return (unsigned short)u;
}
__device__ __forceinline__ float bf2f(unsigned short u) {
  unsigned int v = ((unsigned int)u) << 16;
  return __builtin_bit_cast(float, v);
}
__device__ __forceinline__ float sigf(float x) {
  return __builtin_amdgcn_rcpf(1.0f + __builtin_amdgcn_exp2f(-LOG2E * x));
}
__device__ __forceinline__ float tanhf_(float x) {
  return 1.0f - 2.0f * __builtin_amdgcn_rcpf(1.0f + __builtin_amdgcn_exp2f(2.0f * LOG2E * x));
}
__device__ __forceinline__ void bar_lds() {
  asm volatile("s_waitcnt lgkmcnt(0)" ::: "memory");
  __builtin_amdgcn_s_barrier();
  __builtin_amdgcn_sched_barrier(0);
}
__device__ __forceinline__ void gl_lds16(const void* g, void* l) {
  __builtin_amdgcn_global_load_lds(
      (const __attribute__((address_space(1))) unsigned int*)g,
      (__attribute__((address_space(3))) unsigned int*)l, 16, 0, 0);
}

// ---------------- K1: pack Wi / Wh into B-fragment order (bf16) ---------------
__global__ void pack_kernel(const float* __restrict__ Wi, const float* __restrict__ Wh,
                            unsigned short* __restrict__ Wi_p, unsigned short* __restrict__ Wh_p,
                            unsigned int* __restrict__ flags) {
  if (blockIdx.x == 0 && threadIdx.x < 8) flags[threadIdx.x] = 0u;
  int idx = blockIdx.x * 256 + threadIdx.x;
  if (idx < 262144) {
    int j = idx & 7, lane = (idx >> 3) & 63, nt = (idx >> 9) & 31, kk = idx >> 14;
    int k = kk * 32 + ((lane >> 4) * 8) + j;
    int n = nt * 16 + (lane & 15);
    Wi_p[idx] = f2bf(Wi[k * 512 + n]);
  } else {
    int i2 = idx - 262144;
    int j = i2 & 7, lane = (i2 >> 3) & 63, nt = (i2 >> 9) & 31, kk = i2 >> 14;
    int k = kk * 32 + ((lane >> 4) * 8) + j;
    int n = nt * 16 + (lane & 15);
    Wh_p[i2] = f2bf(Wh[k * 512 + n]);
  }
}

// ---------------- fused: producer GEMM (bids 0..191) + consumer LSTM (192..255)
__global__ __launch_bounds__(512, 2) void fused_kernel(
    const float* __restrict__ x, const unsigned short* __restrict__ Wi_p,
    const float* __restrict__ bias, unsigned int* __restrict__ xg5,
    const unsigned short* __restrict__ Wh_p, const float* __restrict__ Wd,
    const float* __restrict__ bd, float* __restrict__ out,
    unsigned int* __restrict__ flags) {
  __shared__ __align__(16) unsigned short As[128 * 72];        // 18.4 KB (producer)
  __shared__ __align__(16) unsigned short Bs[2 * 32 * 64 * 8]; // 64 KB   (producer)
  __shared__ __align__(16) unsigned short hb[2 * HBUF];        // 9.5 KB  (consumer)

  const int tid = threadIdx.x;
  const int lane = tid & 63;
  const int w = tid >> 6;          // 0..7
  const int quad = lane >> 4;
  const int lm = lane & 15;

  if (blockIdx.x < NPROD) {
    // =========================== PRODUCER ====================================
    const int wm = w >> 2, wn = w & 3;

    float bs_[4][2];
    #pragma unroll
    for (int g = 0; g < 4; ++g)
      #pragma unroll
      for (int jc = 0; jc < 2; ++jc)
        bs_[g][jc] = bias[g * 128 + wn * 32 + jc * 16 + lm];

    for (int t = blockIdx.x; t < 1024; t += NPROD) {
      const int s = t >> 1;
      const int b0 = (t & 1) * 128;

      floatx4 acc[4][8];
      #pragma unroll
      for (int a = 0; a < 4; ++a)
        #pragma unroll
        for (int b2 = 0; b2 < 8; ++b2) { acc[a][b2].x = 0.f; acc[a][b2].y = 0.f; acc[a][b2].z = 0.f; acc[a][b2].w = 0.f; }

      // A rows r = w*16 + i*4 + quad (i 0..3), col lm*4; batch stride 262144 floats.
      const float* xbase = x + ((size_t)(b0 + w * 16 + quad) * 512 + s) * 512 + lm * 4;

      floatx4 cur[4], nxt[4];
      #pragma unroll
      for (int i = 0; i < 4; ++i)
        cur[i] = *(const floatx4*)(xbase + (size_t)i * 1048576);

      for (int kt = 0; kt < 8; ++kt) {
        bar_lds();   // prior compute's LDS reads done; vmcnt NOT drained
        // stage A tile from registers (compiler waits cur's vmcnt here)
        #pragma unroll
        for (int i = 0; i < 4; ++i) {
          int r = w * 16 + i * 4 + quad;
          ushortx4 u;
          u.x = f2bf(cur[i].x); u.y = f2bf(cur[i].y); u.z = f2bf(cur[i].z); u.w = f2bf(cur[i].w);
          *(ushortx4*)(&As[r * 72 + lm * 4]) = u;
        }
        // stage B tile (64 KB) async global->LDS: 8 gl_lds per thread
        #pragma unroll
        for (int c = 0; c < 8; ++c) {
          int kg = c & 1, ntl = (c >> 1) * 8 + w;
          const unsigned short* src = Wi_p + ((size_t)((kt * 2 + kg) * 32 + ntl) * 64 + lane) * 8;
          unsigned short* dst = &Bs[(size_t)((kg * 32 + ntl) * 64) * 8];
          gl_lds16(src, dst);
        }
        // vmcnt(4) below assumes the 8 gl_lds were ISSUED before the 4 A loads.
        __builtin_amdgcn_sched_barrier(0);
        if (kt < 7) {
          #pragma unroll
          for (int i = 0; i < 4; ++i)
            nxt[i] = *(const floatx4*)(xbase + (size_t)i * 1048576 + (kt + 1) * 64);
          asm volatile("s_waitcnt vmcnt(4) lgkmcnt(0)" ::: "memory");
        } else {
          asm volatile("s_waitcnt vmcnt(0) lgkmcnt(0)" ::: "memory");
        }
        __builtin_amdgcn_s_barrier();
        __builtin_amdgcn_sched_barrier(0);   // no ds_read may hoist above barrier
        #pragma unroll
        for (int ks = 0; ks < 2; ++ks) {
          short8 af[4];
          #pragma unroll
          for (int mt = 0; mt < 4; ++mt) {
            int m = wm * 64 + mt * 16 + lm;
            af[mt] = *(const short8*)(&As[m * 72 + ks * 32 + quad * 8]);
          }
          #pragma unroll
          for (int nt = 0; nt < 8; ++nt) {
            int g = nt >> 1, jc = nt & 1;
            int ntl = g * 8 + wn * 2 + jc;
            short8 bfv = *(const short8*)(&Bs[(size_t)((ks * 32 + ntl) * 64 + lane) * 8]);
            #pragma unroll
            for (int mt = 0; mt < 4; ++mt)
              acc[mt][nt] = __builtin_amdgcn_mfma_f32_16x16x32_bf16(af[mt], bfv, acc[mt][nt], 0, 0, 0);
          }
        }
        #pragma unroll
        for (int i = 0; i < 4; ++i) cur[i] = nxt[i];
      }
      // epilogue: per-cell 4-gate 8B RELAXED/AGENT atomic stores (write-through;
      // L2 never holds dirty xg lines).
      #pragma unroll
      for (int mt = 0; mt < 4; ++mt) {
        int bbase = b0 + wm * 64 + mt * 16 + quad * 4;
        #pragma unroll
        for (int jc = 0; jc < 2; ++jc) {
          int wv = wn * 2 + jc;
          #pragma unroll
          for (int rr = 0; rr < 4; ++rr) {
            size_t cell = ((size_t)s * 64 + ((bbase + rr) >> 2)) * 512 + wv * 64 + rr * 16 + lm;
            float g0 = acc[mt][0 + jc][rr] + bs_[0][jc];
            float g1 = acc[mt][2 + jc][rr] + bs_[1][jc];
            float g2 = acc[mt][4 + jc][rr] + bs_[2][jc];
            float g3 = acc[mt][6 + jc][rr] + bs_[3][jc];
            unsigned long long v64 =
                (unsigned long long)((unsigned int)f2bf(g0) | ((unsigned int)f2bf(g1) << 16)) |
                ((unsigned long long)((unsigned int)f2bf(g2) | ((unsigned int)f2bf(g3) << 16)) << 32);
            __hip_atomic_store((unsigned long long*)xg5 + cell, v64,
                               __ATOMIC_RELAXED, __HIP_MEMORY_SCOPE_AGENT);
          }
        }
      }
      // publish: __syncthreads drains every thread's vmcnt (stores acked at the
      // coherence point); one release add per tile.
      __syncthreads();
      __builtin_amdgcn_sched_barrier(0);
      if (tid == 0)
        __hip_atomic_fetch_add(&flags[t >> 7], 1u, __ATOMIC_RELEASE, __HIP_MEMORY_SCOPE_AGENT);
    }
  } else {
    // =========================== CONSUMER ====================================
    const int bb = blockIdx.x - NPROD;

    for (int i = tid; i < 2 * HBUF; i += 512) hb[i] = 0;

    // Wh B-fragments: gate g -> ntg = g*8 + w  (cols g*128 + w*16 + lm).
    // Used as the MFMA *A* operand below (fragment address functions are
    // symmetric), giving C' = (h@Wh)^T.
    short8 bfr[4][4];
    #pragma unroll
    for (int kk = 0; kk < 4; ++kk)
      #pragma unroll
      for (int g = 0; g < 4; ++g)
        bfr[kk][g] = *(const short8*)(Wh_p + ((size_t)(kk * 32 + g * 8 + w) * 64 + lane) * 8);

    // Lane (quad,lm), lm<4 owns 4 cells: batch lm, cols w*16+quad*4+r.
    float cst[4] = {0.f, 0.f, 0.f, 0.f};
    const bool act = (lm < 4);

    // xg u64 index = bb*512 + w*64 + batch*16 + col_lo; per-s stride 32768.
    const unsigned long long* xp =
        (const unsigned long long*)xg5 + ((size_t)bb * 512 + w * 64 + lm * 16 + quad * 4);

    auto at_load8 = [](const unsigned long long* p) -> unsigned long long {
      return __hip_atomic_load(p, __ATOMIC_RELAXED, __HIP_MEMORY_SCOPE_AGENT);
    };

    __syncthreads();   // hb zeros visible

    unsigned long long xga[4], xgb[4];

    auto substep = [&](const int rp, unsigned long long (&xc)[4], int spre) {
      unsigned long long xv[4];
      #pragma unroll
      for (int r = 0; r < 4; ++r) xv[r] = xc[r];

      // h fragment (B operand): 4x ds_read_b128; rows lm (4-15 read zeros).
      short8 af[4];
      #pragma unroll
      for (int kk = 0; kk < 4; ++kk)
        af[kk] = *(const short8*)(&hb[rp * HBUF + lm * HBS + kk * 32 + quad * 8]);

      // xg prefetch (active lanes only; in flight across bar_lds).
      if (spre < 512 && act) {
        #pragma unroll
        for (int r = 0; r < 4; ++r)
          xc[r] = at_load8(xp + (size_t)spre * 32768 + r);
      }

      floatx4 acc[4];
      #pragma unroll
      for (int g = 0; g < 4; ++g) { acc[g].x = 0.f; acc[g].y = 0.f; acc[g].z = 0.f; acc[g].w = 0.f; }
      // SWAPPED operands: C'[gate-col][batch] = Wh^T * h^T.
      #pragma unroll
      for (int kk = 0; kk < 4; ++kk)
        #pragma unroll
        for (int g = 0; g < 4; ++g)
          acc[g] = __builtin_amdgcn_mfma_f32_16x16x32_bf16(bfr[kk][g], af[kk], acc[g], 0, 0, 0);

      // EW directly from accumulator: reg r = cell (batch lm, col w*16+quad*4+r).
      unsigned short hv[4];
      #pragma unroll
      for (int r = 0; r < 4; ++r) {
        float pre0 = acc[0][r] + bf2f((unsigned short)(xv[r] & 0xffffu));
        float pre1 = acc[1][r] + bf2f((unsigned short)((xv[r] >> 16) & 0xffffu));
        float pre2 = acc[2][r] + bf2f((unsigned short)((xv[r] >> 32) & 0xffffu));
        float pre3 = acc[3][r] + bf2f((unsigned short)(xv[r] >> 48));
        float cc = sigf(pre1) * cst[r] + sigf(pre0) * tanhf_(pre2);
        cst[r] = cc;
        hv[r] = f2bf(sigf(pre3) * tanhf_(cc));
      }
      if (act) {
        ushortx4 hv4;
        hv4.x = hv[0]; hv4.y = hv[1]; hv4.z = hv[2]; hv4.w = hv[3];
        *(ushortx4*)(&hb[(rp ^ 1) * HBUF + lm * HBS + w * 16 + quad * 4]) = hv4;
      }
      bar_lds();   // h(s+1) visible to all; vmcnt NOT drained
    };

    for (int c = 0; c < 8; ++c) {
      // wave 0 polls with RELAXED loads (no cache-invalidate side effects).
      if (w == 0) {
        while (__hip_atomic_load(&flags[c], __ATOMIC_RELAXED, __HIP_MEMORY_SCOPE_AGENT) < 128u)
          __builtin_amdgcn_s_sleep(2);
      }
      bar_lds();
      // fresh (re)load of the first two steps of this chunk -- overwrites any
      // tail prefetch that crossed an unpublished boundary.
      if (act) {
        #pragma unroll
        for (int r = 0; r < 4; ++r) {
          xga[r] = at_load8(xp + (size_t)(c * 64) * 32768 + r);
          xgb[r] = at_load8(xp + (size_t)(c * 64 + 1) * 32768 + r);
        }
      }
      #pragma unroll 1
      for (int s2 = 0; s2 < 64; s2 += 2) {
        int s = c * 64 + s2;
        substep(0, xga, s + 2);
        substep(1, xgb, s + 3);
      }
    }

    // head: h_last in hb buf 0 (s=511 writes buf 0)
    if (tid < 8) {
      int rw = tid >> 1, co = tid & 1;
      float a = bd[co];
      for (int j2 = 0; j2 < 128; ++j2)
        a += bf2f(hb[rw * HBS + j2]) * Wd[j2 * 2 + co];
      out[(bb * 4 + rw) * 2 + co] = a;
    }
  }
}

extern "C" void kernel_launch(void* const* d_in, const int* in_sizes, int n_in,
                              void* d_out, int out_size, void* d_ws, size_t ws_size,
                              hipStream_t stream) {
  const float* x  = (const float*)d_in[0];
  const float* Wi = (const float*)d_in[1];
  const float* Wh = (const float*)d_in[2];
  const float* b  = (const float*)d_in[3];
  const float* Wd = (const float*)d_in[4];
  const float* bd = (const float*)d_in[5];
  float* out = (float*)d_out;

  unsigned short* Wi_p = (unsigned short*)d_ws;            // 512 KB
  unsigned short* Wh_p = Wi_p + 262144;                    // 128 KB
  unsigned int*   flags = (unsigned int*)(Wh_p + 65536);   // 512 B (8 used)
  unsigned int*   xg5  = flags + 128;                      // 134.2 MB

  pack_kernel<<<1280, 256, 0, stream>>>(Wi, Wh, Wi_p, Wh_p, flags);
  fused_kernel<<<256, 512, 0, stream>>>(x, Wi_p, b, xg5, Wh_p, Wd, bd, out, flags);
}

// Round 8
// 666.255 us; speedup vs baseline: 1.2355x; 1.2355x over previous
//
#include <hip/hip_runtime.h>
#include <hip/hip_bf16.h>

// LSTM  B=256, S=512, I=512, H=128, OUT=2
// R8: R7 (swapped-operand) REVERTED -- it put all valid C data in 16 lanes and
//     quadrupled EW issue. Base = R6 (412us fused, verified).
//     New model: consumer substep is LDS-PIPE-THROUGHPUT bound (~620cyc/step
//     of LDS occupancy; af reads alone = 32 x ds_read_b128 @12cyc = 384).
//     Rows 4-15 of the af fragment are structurally ZERO (h-writes only touch
//     rows 0-3). Change: af registers zero-initialized ONCE, ds_reads issued
//     under exec mask (lm<4) -- masked lanes keep their zeros forever; the
//     16-active-lane b128 reads cost ~3-4cyc instead of 12. Block af LDS cost
//     384 -> ~100 cyc/substep. MFMA inputs bit-identical.
// R6 retained: hb stride 152 (af = single ds_read_b128), af-first ordering.
// R3 retained: coherence-neutral handshake (RELAXED wave-0 spin; xg via
//     RELAXED/AGENT 8B atomics = write-through / L2-bypass).
// R0 retained: sched_barrier(0) pins gl_lds/prefetch issue order, fences raw
//     s_barrier and same-wave-LDS waits.

typedef __attribute__((ext_vector_type(8))) short short8;      // 8 bf16
typedef __attribute__((ext_vector_type(4))) float floatx4;
typedef __attribute__((ext_vector_type(4))) unsigned short ushortx4;
typedef __attribute__((ext_vector_type(2))) unsigned int uint2v;

#define LOG2E 1.44269504088896340736f
#define NPROD 192
#define HBS 152              // hb row stride (shorts); 304B = 16B-multiple
#define HBUF (16 * HBS)      // one hb buffer (shorts)

__device__ __forceinline__ unsigned short f2bf(float f) {
  unsigned int u = __builtin_bit_cast(unsigned int, f);
  u = (u + 0x7fffu + ((u >> 16) & 1u)) >> 16;   // RNE
  return (unsigned short)u;
}
__device__ __forceinline__ float bf2f(unsigned short u) {
  unsigned int v = ((unsigned int)u) << 16;
  return __builtin_bit_cast(float, v);
}
__device__ __forceinline__ float sigf(float x) {
  return __builtin_amdgcn_rcpf(1.0f + __builtin_amdgcn_exp2f(-LOG2E * x));
}
__device__ __forceinline__ float tanhf_(float x) {
  return 1.0f - 2.0f * __builtin_amdgcn_rcpf(1.0f + __builtin_amdgcn_exp2f(2.0f * LOG2E * x));
}
__device__ __forceinline__ void bar_lds() {
  asm volatile("s_waitcnt lgkmcnt(0)" ::: "memory");
  __builtin_amdgcn_s_barrier();
  __builtin_amdgcn_sched_barrier(0);
}
__device__ __forceinline__ void gl_lds16(const void* g, void* l) {
  __builtin_amdgcn_global_load_lds(
      (const __attribute__((address_space(1))) unsigned int*)g,
      (__attribute__((address_space(3))) unsigned int*)l, 16, 0, 0);
}

// ---------------- K1: pack Wi / Wh into B-fragment order (bf16) ---------------
__global__ void pack_kernel(const float* __restrict__ Wi, const float* __restrict__ Wh,
                            unsigned short* __restrict__ Wi_p, unsigned short* __restrict__ Wh_p,
                            unsigned int* __restrict__ flags) {
  if (blockIdx.x == 0 && threadIdx.x < 8) flags[threadIdx.x] = 0u;
  int idx = blockIdx.x * 256 + threadIdx.x;
  if (idx < 262144) {
    int j = idx & 7, lane = (idx >> 3) & 63, nt = (idx >> 9) & 31, kk = idx >> 14;
    int k = kk * 32 + ((lane >> 4) * 8) + j;
    int n = nt * 16 + (lane & 15);
    Wi_p[idx] = f2bf(Wi[k * 512 + n]);
  } else {
    int i2 = idx - 262144;
    int j = i2 & 7, lane = (i2 >> 3) & 63, nt = (i2 >> 9) & 31, kk = i2 >> 14;
    int k = kk * 32 + ((lane >> 4) * 8) + j;
    int n = nt * 16 + (lane & 15);
    Wh_p[i2] = f2bf(Wh[k * 512 + n]);
  }
}

// ---------------- fused: producer GEMM (bids 0..191) + consumer LSTM (192..255)
__global__ __launch_bounds__(512, 2) void fused_kernel(
    const float* __restrict__ x, const unsigned short* __restrict__ Wi_p,
    const float* __restrict__ bias, unsigned int* __restrict__ xg5,
    const unsigned short* __restrict__ Wh_p, const float* __restrict__ Wd,
    const float* __restrict__ bd, float* __restrict__ out,
    unsigned int* __restrict__ flags) {
  __shared__ __align__(16) unsigned short As[128 * 72];        // 18.4 KB (producer)
  __shared__ __align__(16) unsigned short Bs[2 * 32 * 64 * 8]; // 64 KB   (producer)
  __shared__ __align__(16) unsigned short hb[2 * HBUF];        // 9.5 KB  (consumer)
  __shared__ __align__(16) float gbw[8 * 320];                 // 10 KB   (consumer)

  const int tid = threadIdx.x;
  const int lane = tid & 63;
  const int w = tid >> 6;          // 0..7
  const int quad = lane >> 4;
  const int lm = lane & 15;

  if (blockIdx.x < NPROD) {
    // =========================== PRODUCER ====================================
    const int wm = w >> 2, wn = w & 3;

    float bs_[4][2];
    #pragma unroll
    for (int g = 0; g < 4; ++g)
      #pragma unroll
      for (int jc = 0; jc < 2; ++jc)
        bs_[g][jc] = bias[g * 128 + wn * 32 + jc * 16 + lm];

    for (int t = blockIdx.x; t < 1024; t += NPROD) {
      const int s = t >> 1;
      const int b0 = (t & 1) * 128;

      floatx4 acc[4][8];
      #pragma unroll
      for (int a = 0; a < 4; ++a)
        #pragma unroll
        for (int b2 = 0; b2 < 8; ++b2) { acc[a][b2].x = 0.f; acc[a][b2].y = 0.f; acc[a][b2].z = 0.f; acc[a][b2].w = 0.f; }

      // A rows r = w*16 + i*4 + quad (i 0..3), col lm*4; batch stride 262144 floats.
      const float* xbase = x + ((size_t)(b0 + w * 16 + quad) * 512 + s) * 512 + lm * 4;

      floatx4 cur[4], nxt[4];
      #pragma unroll
      for (int i = 0; i < 4; ++i)
        cur[i] = *(const floatx4*)(xbase + (size_t)i * 1048576);

      for (int kt = 0; kt < 8; ++kt) {
        bar_lds();   // prior compute's LDS reads done; vmcnt NOT drained
        // stage A tile from registers (compiler waits cur's vmcnt here)
        #pragma unroll
        for (int i = 0; i < 4; ++i) {
          int r = w * 16 + i * 4 + quad;
          ushortx4 u;
          u.x = f2bf(cur[i].x); u.y = f2bf(cur[i].y); u.z = f2bf(cur[i].z); u.w = f2bf(cur[i].w);
          *(ushortx4*)(&As[r * 72 + lm * 4]) = u;
        }
        // stage B tile (64 KB) async global->LDS: 8 gl_lds per thread
        #pragma unroll
        for (int c = 0; c < 8; ++c) {
          int kg = c & 1, ntl = (c >> 1) * 8 + w;
          const unsigned short* src = Wi_p + ((size_t)((kt * 2 + kg) * 32 + ntl) * 64 + lane) * 8;
          unsigned short* dst = &Bs[(size_t)((kg * 32 + ntl) * 64) * 8];
          gl_lds16(src, dst);
        }
        // vmcnt(4) below assumes the 8 gl_lds were ISSUED before the 4 A loads.
        __builtin_amdgcn_sched_barrier(0);
        if (kt < 7) {
          #pragma unroll
          for (int i = 0; i < 4; ++i)
            nxt[i] = *(const floatx4*)(xbase + (size_t)i * 1048576 + (kt + 1) * 64);
          asm volatile("s_waitcnt vmcnt(4) lgkmcnt(0)" ::: "memory");
        } else {
          asm volatile("s_waitcnt vmcnt(0) lgkmcnt(0)" ::: "memory");
        }
        __builtin_amdgcn_s_barrier();
        __builtin_amdgcn_sched_barrier(0);   // no ds_read may hoist above barrier
        #pragma unroll
        for (int ks = 0; ks < 2; ++ks) {
          short8 af[4];
          #pragma unroll
          for (int mt = 0; mt < 4; ++mt) {
            int m = wm * 64 + mt * 16 + lm;
            af[mt] = *(const short8*)(&As[m * 72 + ks * 32 + quad * 8]);
          }
          #pragma unroll
          for (int nt = 0; nt < 8; ++nt) {
            int g = nt >> 1, jc = nt & 1;
            int ntl = g * 8 + wn * 2 + jc;
            short8 bfv = *(const short8*)(&Bs[(size_t)((ks * 32 + ntl) * 64 + lane) * 8]);
            #pragma unroll
            for (int mt = 0; mt < 4; ++mt)
              acc[mt][nt] = __builtin_amdgcn_mfma_f32_16x16x32_bf16(af[mt], bfv, acc[mt][nt], 0, 0, 0);
          }
        }
        #pragma unroll
        for (int i = 0; i < 4; ++i) cur[i] = nxt[i];
      }
      // epilogue: per-cell 4-gate 8B RELAXED/AGENT atomic stores (write-through;
      // L2 never holds dirty xg lines).
      #pragma unroll
      for (int mt = 0; mt < 4; ++mt) {
        int bbase = b0 + wm * 64 + mt * 16 + quad * 4;
        #pragma unroll
        for (int jc = 0; jc < 2; ++jc) {
          int wv = wn * 2 + jc;
          #pragma unroll
          for (int rr = 0; rr < 4; ++rr) {
            size_t cell = ((size_t)s * 64 + ((bbase + rr) >> 2)) * 512 + wv * 64 + rr * 16 + lm;
            float g0 = acc[mt][0 + jc][rr] + bs_[0][jc];
            float g1 = acc[mt][2 + jc][rr] + bs_[1][jc];
            float g2 = acc[mt][4 + jc][rr] + bs_[2][jc];
            float g3 = acc[mt][6 + jc][rr] + bs_[3][jc];
            unsigned long long v64 =
                (unsigned long long)((unsigned int)f2bf(g0) | ((unsigned int)f2bf(g1) << 16)) |
                ((unsigned long long)((unsigned int)f2bf(g2) | ((unsigned int)f2bf(g3) << 16)) << 32);
            __hip_atomic_store((unsigned long long*)xg5 + cell, v64,
                               __ATOMIC_RELAXED, __HIP_MEMORY_SCOPE_AGENT);
          }
        }
      }
      // publish: __syncthreads drains every thread's vmcnt (stores acked at the
      // coherence point); one release add per tile.
      __syncthreads();
      __builtin_amdgcn_sched_barrier(0);
      if (tid == 0)
        __hip_atomic_fetch_add(&flags[t >> 7], 1u, __ATOMIC_RELEASE, __HIP_MEMORY_SCOPE_AGENT);
    }
  } else {
    // =========================== CONSUMER ====================================
    const int bb = blockIdx.x - NPROD;

    for (int i = tid; i < 2 * HBUF; i += 512) hb[i] = 0;

    // Wh B-fragments: gate g -> ntg = g*8 + w  (cols g*128 + w*16 + lm)
    short8 bfr[4][4];
    #pragma unroll
    for (int kk = 0; kk < 4; ++kk)
      #pragma unroll
      for (int g = 0; g < 4; ++g)
        bfr[kk][g] = *(const short8*)(Wh_p + ((size_t)(kk * 32 + g * 8 + w) * 64 + lane) * 8);

    float cst = 0.f;   // cell state for (row quad, col w*16+lm)

    // xg: cell index within block = tid; per-s stride = 64*512 cells = 32768 u64
    const unsigned long long* xp = (const unsigned long long*)xg5 + ((size_t)bb * 512 + tid);
    float* gw = gbw + w * 320;

    auto at_load8 = [](const unsigned long long* p) -> uint2v {
      unsigned long long v = __hip_atomic_load(p, __ATOMIC_RELAXED, __HIP_MEMORY_SCOPE_AGENT);
      uint2v r; r.x = (unsigned int)v; r.y = (unsigned int)(v >> 32); return r;
    };

    // A-fragment registers: rows 4-15 of h are structurally zero (h-writes
    // only touch rows 0-3). Zero-init ONCE; the per-substep ds_reads are
    // exec-masked to lm<4 so masked lanes keep their zeros forever. This
    // cuts the dominant LDS-pipe cost (32 full-wave b128 reads/substep ->
    // 16-active-lane reads).
    short8 af[4] = {};

    __syncthreads();   // hb zeros visible

    uint2v xga, xgb;

    auto substep = [&](const int rp, uint2v& xcur, int spre) {
      uint2v xv = xcur;

      // A-frags (rows 0-3 only): 4x ds_read_b128 under exec mask lm<4.
      if (lm < 4) {
        #pragma unroll
        for (int kk = 0; kk < 4; ++kk)
          af[kk] = *(const short8*)(&hb[rp * HBUF + lm * HBS + kk * 32 + quad * 8]);
      }

      // xg prefetch issued after the af reads (independent; in flight across
      // bar_lds -- vmcnt not drained by it).
      if (spre < 512)
        xcur = at_load8(xp + (size_t)spre * 32768);

      floatx4 acc[4];
      #pragma unroll
      for (int g = 0; g < 4; ++g) { acc[g].x = 0.f; acc[g].y = 0.f; acc[g].z = 0.f; acc[g].w = 0.f; }
      #pragma unroll
      for (int kk = 0; kk < 4; ++kk)
        #pragma unroll
        for (int g = 0; g < 4; ++g)
          acc[g] = __builtin_amdgcn_mfma_f32_16x16x32_bf16(af[kk], bfr[kk][g], acc[g], 0, 0, 0);

      // intra-wave transpose: quad0 (rows 0-3 of C) -> [lm][r] gate-vectors
      if (lane < 16) {
        #pragma unroll
        for (int r = 0; r < 4; ++r) {
          floatx4 t4;
          t4.x = acc[0][r]; t4.y = acc[1][r]; t4.z = acc[2][r]; t4.w = acc[3][r];
          *(floatx4*)(gw + lm * 20 + r * 4) = t4;
        }
      }
      asm volatile("s_waitcnt lgkmcnt(0)" ::: "memory");   // same-wave DS order
      __builtin_amdgcn_sched_barrier(0);                   // rule-18 fence
      floatx4 gv = *(const floatx4*)(gw + lm * 20 + quad * 4);

      // EW: 1 cell/lane
      float pre0 = gv.x + bf2f((unsigned short)(xv.x & 0xffffu));
      float pre1 = gv.y + bf2f((unsigned short)(xv.x >> 16));
      float pre2 = gv.z + bf2f((unsigned short)(xv.y & 0xffffu));
      float pre3 = gv.w + bf2f((unsigned short)(xv.y >> 16));
      float cc = sigf(pre1) * cst + sigf(pre0) * tanhf_(pre2);
      cst = cc;
      float hv = sigf(pre3) * tanhf_(cc);
      hb[(rp ^ 1) * HBUF + quad * HBS + w * 16 + lm] = f2bf(hv);
      bar_lds();   // h(s+1) visible to all; vmcnt NOT drained
    };

    for (int c = 0; c < 8; ++c) {
      // wave 0 polls with RELAXED loads (no cache-invalidate side effects).
      if (w == 0) {
        while (__hip_atomic_load(&flags[c], __ATOMIC_RELAXED, __HIP_MEMORY_SCOPE_AGENT) < 128u)
          __builtin_amdgcn_s_sleep(2);
      }
      bar_lds();
      // fresh (re)load of the first two steps of this chunk -- overwrites any
      // tail prefetch that crossed an unpublished boundary.
      xga = at_load8(xp + (size_t)(c * 64) * 32768);
      xgb = at_load8(xp + (size_t)(c * 64 + 1) * 32768);
      #pragma unroll 1
      for (int s2 = 0; s2 < 64; s2 += 2) {
        int s = c * 64 + s2;
        substep(0, xga, s + 2);
        substep(1, xgb, s + 3);
      }
    }

    // head: h_last in hb buf 0 (s=511 writes buf 0)
    if (tid < 8) {
      int rw = tid >> 1, co = tid & 1;
      float a = bd[co];
      for (int j2 = 0; j2 < 128; ++j2)
        a += bf2f(hb[rw * HBS + j2]) * Wd[j2 * 2 + co];
      out[(bb * 4 + rw) * 2 + co] = a;
    }
  }
}

extern "C" void kernel_launch(void* const* d_in, const int* in_sizes, int n_in,
                              void* d_out, int out_size, void* d_ws, size_t ws_size,
                              hipStream_t stream) {
  const float* x  = (const float*)d_in[0];
  const float* Wi = (const float*)d_in[1];
  const float* Wh = (const float*)d_in[2];
  const float* b  = (const float*)d_in[3];
  const float* Wd = (const float*)d_in[4];
  const float* bd = (const float*)d_in[5];
  float* out = (float*)d_out;

  unsigned short* Wi_p = (unsigned short*)d_ws;            // 512 KB
  unsigned short* Wh_p = Wi_p + 262144;                    // 128 KB
  unsigned int*   flags = (unsigned int*)(Wh_p + 65536);   // 512 B (8 used)
  unsigned int*   xg5  = flags + 128;                      // 134.2 MB

  pack_kernel<<<1280, 256, 0, stream>>>(Wi, Wh, Wi_p, Wh_p, flags);
  fused_kernel<<<256, 512, 0, stream>>>(x, Wi_p, b, xg5, Wh_p, Wd, bd, out, flags);
}